// Round 9
// baseline (403.555 us; speedup 1.0000x reference)
//
#include <hip/hip_runtime.h>

#define BB 8
#define CC 64
#define HH 128
#define WW 128
#define TT 3
#define LL 4
#define MM 3
#define STRD 72            // halves per px (64 ch + 8 pad) -> 144 B stride, 16B-aligned

// LDS layout (halves):
#define BUFA 0             // 576*72 = 41472  (24x24 patch; layer-1 out)
#define BUFB 41472         // 484*72 = 34848  (layer-0 out 22x22; layer-2 out 18x18)
#define BLDS_OFF 76320     // 256 floats (bias 4x64) = 512 halves
#define SMEM_BYTES 153664  // (76320+512)*2

typedef _Float16 half8 __attribute__((ext_vector_type(8)));
typedef _Float16 half4 __attribute__((ext_vector_type(4)));
typedef float floatx16 __attribute__((ext_vector_type(16)));

// ---------------------------------------------------------------------------
// Routing chain: argmax over (a + g), chained on prev index.
// (log_softmax(a)+g)/tau is a monotone transform of (a+g).
// ---------------------------------------------------------------------------
__device__ inline void compute_sel(const float* __restrict__ alpha0,
                                   const float* __restrict__ alphas,
                                   const float* __restrict__ g0,
                                   const float* __restrict__ gs,
                                   int* sel_local) {
    for (int t = 0; t < TT; ++t) {
        int idx = 0;
        for (int layer = 0; layer < LL; ++layer) {
            const float *a, *g;
            if (layer == 0) { a = alpha0 + t * MM; g = g0 + t * MM; }
            else {
                int off = (((layer - 1) * TT + t) * MM + idx) * MM;
                a = alphas + off; g = gs + off;
            }
            float best = a[0] + g[0];
            int bi = 0;
            for (int j = 1; j < MM; ++j) {
                float v = a[j] + g[j];
                if (v > best) { best = v; bi = j; }
            }
            sel_local[t * LL + layer] = bi;
            idx = bi;
        }
    }
}

// ---------------------------------------------------------------------------
// Weight prep (layout proven in R6): W3[tl][s=kc*9+tap][m][lane][8];
// lane l of frag (s,m): oc = m*32+(l&31), k = kc*16+(l>>5)*8+j.
// Also emits bias table Bsel[tl][64].
// ---------------------------------------------------------------------------
__global__ __launch_bounds__(256) void prep_weights(
    const float* __restrict__ enc_w, // [L][M][64][64][3][3]
    const float* __restrict__ enc_b, // [L][M][64]
    const float* __restrict__ alpha0,
    const float* __restrict__ alphas,
    const float* __restrict__ g0,
    const float* __restrict__ gs,
    _Float16* __restrict__ W3,       // [12][36864]
    float* __restrict__ Bsel)        // [12][64]
{
    int sel_local[TT * LL];
    compute_sel(alpha0, alphas, g0, gs, sel_local);

    int tl = blockIdx.y;             // t*4 + layer
    int layer = tl & 3;
    int m_sel = sel_local[tl];

    const float* src = enc_w + ((size_t)layer * MM + m_sel) * (CC * CC * 9);
    _Float16* dst = W3 + (size_t)tl * 36864;
    for (int i = blockIdx.x * 256 + threadIdx.x; i < 36864; i += gridDim.x * 256) {
        int j  = i & 7;
        int l  = (i >> 3) & 63;
        int m  = (i >> 9) & 1;
        int q  = i >> 10;            // s = kc*9 + tap
        int tap = q % 9;
        int kc  = q / 9;
        int oc  = m * 32 + (l & 31);
        int kch = kc * 16 + (l >> 5) * 8 + j;
        dst[i] = (_Float16)src[(oc * CC + kch) * 9 + tap];
    }
    if (blockIdx.x == 0 && threadIdx.x < CC)
        Bsel[tl * CC + threadIdx.x] = enc_b[((size_t)layer * MM + m_sel) * CC + threadIdx.x];
}

// ---------------------------------------------------------------------------
// x: NCHW fp32 -> NHWC f16 (proven R4-R6).
// ---------------------------------------------------------------------------
__global__ __launch_bounds__(256) void to_nhwc(
    const float* __restrict__ x,    // [B][64][128][128]
    _Float16* __restrict__ act0)    // [B][128][128][64]
{
    const int xs = blockIdx.x;
    const int y  = blockIdx.y;
    const int b  = blockIdx.z;

    __shared__ _Float16 lds[64 * 72];

    const int wv = threadIdx.x >> 6;
    const int l  = threadIdx.x & 63;
    const float* src = x + ((size_t)b * CC * HH + y) * WW + xs * 64 + l;
#pragma unroll
    for (int k = 0; k < 16; ++k) {
        int ch = wv * 16 + k;
        lds[l * 72 + ch] = (_Float16)src[(size_t)ch * HH * WW];
    }
    __syncthreads();
    int px = threadIdx.x >> 2;
    int q  = threadIdx.x & 3;
    _Float16* dst = act0 + (((size_t)b * HH + y) * WW + xs * 64 + px) * CC + q * 16;
    *(half8*)dst       = *(const half8*)&lds[px * 72 + q * 16];
    *(half8*)(dst + 8) = *(const half8*)&lds[px * 72 + q * 16 + 8];
}

// ---------------------------------------------------------------------------
// Fully-fused 4-layer conv + decoder. One block = 16x16 output tile of one
// (b, task). Activations LDS-resident: 24x24 patch -> 22 -> 20 -> 18 -> 16.
// SAME-padding semantics restored: activations at out-of-image positions are
// forced to zero after every layer (the R7/R8 bug was leaving them nonzero).
// Weights: per-wave global frag loads with depth-1 rolling prefetch.
// ---------------------------------------------------------------------------
__global__ __launch_bounds__(256, 1) void fused_net(
    const _Float16* __restrict__ act0,  // [B][H][W][64] f16
    float* __restrict__ out,            // [T][B][3][H][W] fp32
    const _Float16* __restrict__ W3,    // [12][36864]
    const float* __restrict__ Bsel,     // [12][64]
    const float* __restrict__ dec_w,    // [T][3][64]
    const float* __restrict__ dec_b)    // [T][3]
{
    extern __shared__ __align__(16) _Float16 smem[];
    float* Blds = (float*)(smem + BLDS_OFF);

    const int tile = blockIdx.x;        // 0..63
    const int b    = blockIdx.y;
    const int t    = blockIdx.z;
    const int ty = tile >> 3, tx = tile & 7;

    const int tid  = threadIdx.x;
    const int lane = tid & 63;
    const int w    = tid >> 6;
    const int n    = lane & 31;
    const int ksub = lane >> 5;

    const _Float16* inp   = act0 + (size_t)b * (HH * WW * CC);
    const _Float16* Wtask = W3 + (size_t)t * 4 * 36864;

    // ---- stage 24x24 x 64ch input patch (zero outside image) ----
    {
        const int y0g = ty * 16 - 4, x0g = tx * 16 - 4;
#pragma unroll
        for (int k = 0; k < 18; ++k) {
            int idx = tid + (k << 8);        // 0..4607 = 576 px * 8 ch-groups
            int px = idx >> 3, c8 = idx & 7;
            int gy = y0g + px / 24;
            int gx = x0g + px % 24;
            half8 v = {};
            if ((unsigned)gy < HH && (unsigned)gx < WW)
                v = *(const half8*)(inp + ((size_t)(gy * WW + gx)) * CC + c8 * 8);
            *(half8*)(smem + BUFA + px * STRD + c8 * 8) = v;
        }
    }
    Blds[tid] = Bsel[t * 256 + tid];
    __syncthreads();

    floatx16 acc[4][2];

#pragma unroll
    for (int layer = 0; layer < 4; ++layer) {
        const int Win  = 24 - 2 * layer;
        const int Wo   = Win - 2;
        const int NpxO = Wo * Wo;
        const int NTl  = (NpxO + 31) >> 5;
        const int bin  = (layer & 1) ? BUFB : BUFA;
        const int bout = (layer & 1) ? BUFA : BUFB;
        const _Float16* Wl = Wtask + (size_t)layer * 36864;

        int ibase[4], pxv[4];
#pragma unroll
        for (int i = 0; i < 4; ++i) {
            int px = (w + 4 * i) * 32 + n;
            pxv[i] = px;
            int pxc = px < NpxO ? px : NpxO - 1;
            int y = pxc / Wo, x = pxc - y * Wo;
            ibase[i] = bin + (y * Win + x) * STRD + ksub * 8;
#pragma unroll
            for (int e = 0; e < 16; ++e) { acc[i][0][e] = 0.f; acc[i][1][e] = 0.f; }
        }

        half8 a0c = *(const half8*)(Wl + lane * 8);
        half8 a1c = *(const half8*)(Wl + 512 + lane * 8);
        for (int kc = 0; kc < 4; ++kc) {
#pragma unroll
            for (int tap = 0; tap < 9; ++tap) {
                const int s = kc * 9 + tap;
                half8 a0n, a1n;
                if (s + 1 < 36) {
                    const _Float16* wp = Wl + (s + 1) * 1024 + lane * 8;
                    a0n = *(const half8*)wp;
                    a1n = *(const half8*)(wp + 512);
                }
                const int dy = tap / 3, dx = tap - 3 * dy;
                const int toff = (dy * Win + dx) * STRD + kc * 16;
#pragma unroll
                for (int i = 0; i < 4; ++i) {
                    if (w + 4 * i < NTl) {
                        half8 bb = *(const half8*)(smem + ibase[i] + toff);
                        acc[i][0] = __builtin_amdgcn_mfma_f32_32x32x16_f16(a0c, bb, acc[i][0], 0, 0, 0);
                        acc[i][1] = __builtin_amdgcn_mfma_f32_32x32x16_f16(a1c, bb, acc[i][1], 0, 0, 0);
                    }
                }
                if (s + 1 < 36) { a0c = a0n; a1c = a1n; }
            }
        }

        if (layer < 3) {
            // bias + ReLU -> f16 -> bout, ZEROED at out-of-image positions
            // (layer-l output grid origin = tile origin - (3-l))
            const int og = 3 - layer;
#pragma unroll
            for (int i = 0; i < 4; ++i) {
                if (pxv[i] < NpxO) {
                    int py  = pxv[i] / Wo;
                    int pxl = pxv[i] - py * Wo;
                    int gy = ty * 16 - og + py;
                    int gx = tx * 16 - og + pxl;
                    bool inimg = ((unsigned)gy < HH) && ((unsigned)gx < WW);
                    _Float16* po = smem + bout + pxv[i] * STRD;
#pragma unroll
                    for (int m = 0; m < 2; ++m)
#pragma unroll
                        for (int rg = 0; rg < 4; ++rg) {
                            int oc = m * 32 + 4 * ksub + 8 * rg;
                            half4 h;
#pragma unroll
                            for (int k2 = 0; k2 < 4; ++k2)
                                h[k2] = (_Float16)(inimg
                                    ? fmaxf(acc[i][m][rg * 4 + k2] + Blds[layer * 64 + oc + k2], 0.f)
                                    : 0.f);
                            *(half4*)(po + oc) = h;
                        }
                }
            }
            __syncthreads();
        } else {
            // fused decoder: relu(conv3+bias) -> 1x1 conv 64->3 -> (norm) -> NCHW fp32
            const float* dwp = dec_w + (size_t)t * 3 * CC;
#pragma unroll
            for (int i = 0; i < 2; ++i) {
                float s0 = 0.f, s1 = 0.f, s2 = 0.f;
#pragma unroll
                for (int m = 0; m < 2; ++m)
#pragma unroll
                    for (int rg = 0; rg < 4; ++rg)
#pragma unroll
                        for (int k2 = 0; k2 < 4; ++k2) {
                            int oc = m * 32 + 4 * ksub + 8 * rg + k2;
                            float v = fmaxf(acc[i][m][rg * 4 + k2] + Blds[192 + oc], 0.f);
                            s0 += v * dwp[oc];
                            s1 += v * dwp[CC + oc];
                            s2 += v * dwp[2 * CC + oc];
                        }
                s0 += __shfl_xor(s0, 32);
                s1 += __shfl_xor(s1, 32);
                s2 += __shfl_xor(s2, 32);
                if (ksub == 0) {
                    s0 += dec_b[t * 3 + 0];
                    s1 += dec_b[t * 3 + 1];
                    s2 += dec_b[t * 3 + 2];
                    if (t == 2) {
                        float r = 1.0f / sqrtf(s0 * s0 + s1 * s1 + s2 * s2);
                        s0 *= r; s1 *= r; s2 *= r;
                    }
                    int px = (w + 4 * i) * 32 + n;     // 0..255
                    int gy = ty * 16 + (px >> 4);
                    int gx = tx * 16 + (px & 15);
                    float* ob = out + (size_t)(t * BB + b) * 3 * (HH * WW)
                                    + (size_t)gy * WW + gx;
                    ob[0]           = s0;
                    ob[HH * WW]     = s1;
                    ob[2 * HH * WW] = s2;
                }
            }
        }
    }
}

extern "C" void kernel_launch(void* const* d_in, const int* in_sizes, int n_in,
                              void* d_out, int out_size, void* d_ws, size_t ws_size,
                              hipStream_t stream) {
    const float* x      = (const float*)d_in[0];
    const float* alpha0 = (const float*)d_in[1];
    const float* alphas = (const float*)d_in[2];
    const float* g0     = (const float*)d_in[3];
    const float* gs     = (const float*)d_in[4];
    const float* enc_w  = (const float*)d_in[5];
    const float* enc_b  = (const float*)d_in[6];
    const float* dec_w  = (const float*)d_in[7];
    const float* dec_b  = (const float*)d_in[8];
    float* out = (float*)d_out;

    char* pw = (char*)d_ws;
    float* Bsel = (float*)pw;            pw += 4096;
    _Float16* W3 = (_Float16*)pw;        pw += (size_t)12 * 36864 * 2;   // 884,736 B
    _Float16* act0 = (_Float16*)pw;      // 16.8 MB

    (void)hipFuncSetAttribute((const void*)fused_net,
                              hipFuncAttributeMaxDynamicSharedMemorySize, SMEM_BYTES);

    prep_weights<<<dim3(36, 12), 256, 0, stream>>>(enc_w, enc_b, alpha0, alphas, g0, gs, W3, Bsel);
    to_nhwc<<<dim3(2, HH, BB), 256, 0, stream>>>(x, act0);
    fused_net<<<dim3(64, BB, TT), 256, SMEM_BYTES, stream>>>(act0, out, W3, Bsel, dec_w, dec_b);
}